// Round 1
// baseline (621.309 us; speedup 1.0000x reference)
//
#include <hip/hip_runtime.h>
#include <hip/hip_bf16.h>
#include <stdint.h>

typedef __attribute__((ext_vector_type(4))) short short4v;
typedef __attribute__((ext_vector_type(8))) short short8v;
typedef __attribute__((ext_vector_type(4))) float float4v;

#define NN 8192
#define FIN 256
#define FOUT 256

__device__ __forceinline__ short f2bf(float f) {
    unsigned u = __float_as_uint(f);
    unsigned r = u + 0x7fffu + ((u >> 16) & 1u);   // RNE
    return (short)(r >> 16);
}

// W [256][256] fp32 -> WT [n][k] bf16
__global__ __launch_bounds__(256) void k_wt(const float* __restrict__ W, short* __restrict__ WT) {
    int k = blockIdx.x, n = threadIdx.x;
    WT[n * 256 + k] = f2bf(W[k * 256 + n]);
}

// Wh = h @ W  (M=8192, N=256, K=256), bf16 MFMA, 64x64 tile, BK=32
__global__ __launch_bounds__(256) void k_gemm1(const float* __restrict__ h, const short* __restrict__ WT,
                                               float* __restrict__ Wh) {
    __shared__ short sA[64 * 40];
    __shared__ short sB[64 * 40];
    int bm = blockIdx.x;   // 0..127
    int bn = blockIdx.y;   // 0..3
    int t  = threadIdx.x;
    int w = t >> 6, lane = t & 63, quad = lane >> 4, l16 = lane & 15;

    float4v acc[4];
#pragma unroll
    for (int c = 0; c < 4; c++)
#pragma unroll
        for (int j = 0; j < 4; j++) acc[c][j] = 0.f;

    int r  = t >> 2;            // 0..63
    int ko = (t & 3) * 8;       // 0,8,16,24

    for (int k0 = 0; k0 < 256; k0 += 32) {
        // stage A: h rows 64*bm.. , cols k0..k0+31 -> bf16
        const float4v* src = (const float4v*)&h[(size_t)(64 * bm + r) * 256 + k0 + ko];
        float4v v0 = src[0], v1 = src[1];
        short8v pk;
        pk[0] = f2bf(v0[0]); pk[1] = f2bf(v0[1]); pk[2] = f2bf(v0[2]); pk[3] = f2bf(v0[3]);
        pk[4] = f2bf(v1[0]); pk[5] = f2bf(v1[1]); pk[6] = f2bf(v1[2]); pk[7] = f2bf(v1[3]);
        *(short8v*)&sA[r * 40 + ko] = pk;
        // stage B: WT rows 64*bn.. (cols of W), k chunk
        short8v bv = *(const short8v*)&WT[(size_t)(64 * bn + r) * 256 + k0 + ko];
        *(short8v*)&sB[r * 40 + ko] = bv;
        __syncthreads();

        short8v af = *(const short8v*)&sA[(16 * w + l16) * 40 + quad * 8];
#pragma unroll
        for (int c = 0; c < 4; c++) {
            short8v bf = *(const short8v*)&sB[(16 * c + l16) * 40 + quad * 8];
            acc[c] = __builtin_amdgcn_mfma_f32_16x16x32_bf16(af, bf, acc[c], 0, 0, 0);
        }
        __syncthreads();
    }
#pragma unroll
    for (int c = 0; c < 4; c++)
#pragma unroll
        for (int j = 0; j < 4; j++) {
            int row = 64 * bm + 16 * w + quad * 4 + j;
            int col = 64 * bn + 16 * c + l16;
            Wh[(size_t)row * 256 + col] = acc[c][j];
        }
}

// Wh1 = Wh@a1, Wh2 = Wh@a2, global max(Wh2) via encoded atomicMax. 4 rows/block (1/wave).
__global__ __launch_bounds__(256) void k_rowstats(const float* __restrict__ Wh, const float* __restrict__ a,
                                                  float* __restrict__ Wh1, float* __restrict__ Wh2,
                                                  unsigned* __restrict__ maxenc) {
    int w = threadIdx.x >> 6, lane = threadIdx.x & 63;
    int row = blockIdx.x * 4 + w;
    float s1 = 0.f, s2 = 0.f;
#pragma unroll
    for (int j = 0; j < 4; j++) {
        int c = lane + 64 * j;
        float v = Wh[(size_t)row * 256 + c];
        s1 += v * a[c];
        s2 += v * a[256 + c];
    }
#pragma unroll
    for (int off = 32; off; off >>= 1) {
        s1 += __shfl_down(s1, off);
        s2 += __shfl_down(s2, off);
    }
    if (lane == 0) {
        Wh1[row] = s1;
        Wh2[row] = s2;
        unsigned u = __float_as_uint(s2);
        unsigned key = (u & 0x80000000u) ? ~u : (u | 0x80000000u);
        atomicMax(maxenc, key);
    }
}

// WhT[n][k] bf16 from Wh[k][n] fp32, 64x64 LDS tile
__global__ __launch_bounds__(256) void k_transpose(const float* __restrict__ Wh, short* __restrict__ WhT) {
    __shared__ short sT[64 * 72];
    int bm = blockIdx.x, bn = blockIdx.y;
    int t = threadIdx.x;
#pragma unroll
    for (int i = 0; i < 4; i++) {
        int idx = i * 256 + t;
        int r = idx >> 4, c4 = (idx & 15) * 4;
        float4v v = *(const float4v*)&Wh[(size_t)(64 * bm + r) * 256 + 64 * bn + c4];
#pragma unroll
        for (int j = 0; j < 4; j++) sT[(c4 + j) * 72 + r] = f2bf(v[j]);
    }
    __syncthreads();
    int c = t >> 2, ro = (t & 3) * 16;
#pragma unroll
    for (int hh = 0; hh < 2; hh++) {
        short8v v = *(const short8v*)&sT[c * 72 + ro + 8 * hh];
        *(short8v*)&WhT[(size_t)(64 * bn + c) * 8192 + 64 * bm + ro + 8 * hh] = v;
    }
}

// Fused: P = masked softmax-numerator from adj + rank-1 scores; out = elu((P @ Wh) / rowsum(P))
// 256 blocks x 512 threads. M-tile 32, N 256, BK 64.
__global__ __launch_bounds__(512) void k_gat(const float* __restrict__ adj, const short* __restrict__ WhT,
                                             const float* __restrict__ Wh1, const float* __restrict__ Wh2,
                                             const unsigned* __restrict__ maxenc, float* __restrict__ out) {
    __shared__ short sA[32 * 72];
    __shared__ short sB[256 * 72];
    __shared__ float s_l[32];
    int b = blockIdx.x;
    int t = threadIdx.x;
    int lane = t & 63, quad = lane >> 4, l16 = lane & 15;
    int w = t >> 6;
    int rg = w & 1;        // row-group 0/1 (16 rows each)
    int cg = w >> 1;       // col-group 0..3 (64 cols each)

    // decode global max(Wh2)
    unsigned key = maxenc[0];
    unsigned u = (key & 0x80000000u) ? (key & 0x7fffffffu) : ~key;
    float maxw2 = __uint_as_float(u);

    int r  = t >> 4;          // staging row 0..31
    int kc = (t & 15) * 4;    // staging k offset 0..60
    float wh1r = Wh1[32 * b + r];
    float sup = wh1r + maxw2;
    float ci = fmaxf(sup, 0.2f * sup);   // f monotone => e_ij <= ci for all j

    const float* adj_row = &adj[(size_t)(32 * b + r) * 8192];

    float4v acc[4];
#pragma unroll
    for (int c = 0; c < 4; c++)
#pragma unroll
        for (int j = 0; j < 4; j++) acc[c][j] = 0.f;
    float lsum = 0.f;

    for (int k0 = 0; k0 < 8192; k0 += 64) {
        // ---- stage A: compute P tile [32 x 64] from adj + rank-1 scores
        float4v av = *(const float4v*)&adj_row[k0 + kc];
        float4v w2 = *(const float4v*)&Wh2[k0 + kc];
        short4v pk;
#pragma unroll
        for (int j = 0; j < 4; j++) {
            float s = wh1r + w2[j];
            float f = fmaxf(s, 0.2f * s);        // leaky_relu(0.2)
            float p = __expf(f - ci);
            p = (av[j] > 0.f) ? p : 0.f;
            lsum += p;
            pk[j] = f2bf(p);
        }
        *(short4v*)&sA[r * 72 + kc] = pk;
        // ---- stage B: WhT rows (cols of Wh), 256 x 64 bf16
#pragma unroll
        for (int i = 0; i < 4; i++) {
            int idx = i * 512 + t;
            int n = idx >> 3, off8 = (idx & 7) * 8;
            short8v bv = *(const short8v*)&WhT[(size_t)n * 8192 + k0 + off8];
            *(short8v*)&sB[n * 72 + off8] = bv;
        }
        __syncthreads();
#pragma unroll
        for (int kk = 0; kk < 2; kk++) {
            short8v af = *(const short8v*)&sA[(16 * rg + l16) * 72 + kk * 32 + quad * 8];
#pragma unroll
            for (int c = 0; c < 4; c++) {
                short8v bf = *(const short8v*)&sB[(64 * cg + 16 * c + l16) * 72 + kk * 32 + quad * 8];
                acc[c] = __builtin_amdgcn_mfma_f32_16x16x32_bf16(af, bf, acc[c], 0, 0, 0);
            }
        }
        __syncthreads();
    }

    // reduce lsum across the 16 staging threads that share a row
#pragma unroll
    for (int off = 8; off; off >>= 1) lsum += __shfl_xor(lsum, off, 16);
    if ((lane & 15) == 0) s_l[r] = lsum;
    __syncthreads();

#pragma unroll
    for (int c = 0; c < 4; c++)
#pragma unroll
        for (int j = 0; j < 4; j++) {
            int rl = 16 * rg + quad * 4 + j;
            float l = fmaxf(s_l[rl], 1e-30f);
            float v = acc[c][j] / l;
            float o = (v > 0.f) ? v : (__expf(v) - 1.f);   // elu
            out[(size_t)(32 * b + rl) * 256 + 64 * cg + 16 * c + l16] = o;
        }
}

extern "C" void kernel_launch(void* const* d_in, const int* in_sizes, int n_in,
                              void* d_out, int out_size, void* d_ws, size_t ws_size,
                              hipStream_t stream) {
    const float* h   = (const float*)d_in[0];
    const float* adj = (const float*)d_in[1];
    const float* W   = (const float*)d_in[2];
    const float* a   = (const float*)d_in[3];
    float* out = (float*)d_out;

    char* ws = (char*)d_ws;
    float*    Wh     = (float*)(ws);                          // 8 MB
    short*    WhT    = (short*)(ws + 8388608);                // 4 MB
    short*    WT     = (short*)(ws + 12582912);               // 128 KB
    float*    Wh1    = (float*)(ws + 12713984);               // 32 KB
    float*    Wh2    = (float*)(ws + 12746752);               // 32 KB
    unsigned* maxenc = (unsigned*)(ws + 12779520);            // 4 B

    hipMemsetAsync(maxenc, 0, sizeof(unsigned), stream);

    k_wt<<<256, 256, 0, stream>>>(W, WT);
    k_gemm1<<<dim3(128, 4), 256, 0, stream>>>(h, WT, Wh);
    k_rowstats<<<2048, 256, 0, stream>>>(Wh, a, Wh1, Wh2, maxenc);
    k_transpose<<<dim3(128, 4), 256, 0, stream>>>(Wh, WhT);
    k_gat<<<256, 512, 0, stream>>>(adj, WhT, Wh1, Wh2, maxenc, out);
}

// Round 3
// 546.726 us; speedup vs baseline: 1.1364x; 1.1364x over previous
//
#include <hip/hip_runtime.h>
#include <hip/hip_bf16.h>
#include <stdint.h>

typedef __attribute__((ext_vector_type(4))) short short4v;
typedef __attribute__((ext_vector_type(8))) short short8v;
typedef __attribute__((ext_vector_type(4))) float float4v;

#define NN 8192
#define FIN 256
#define FOUT 256

__device__ __forceinline__ short f2bf(float f) {
    unsigned u = __float_as_uint(f);
    unsigned r = u + 0x7fffu + ((u >> 16) & 1u);   // RNE
    return (short)(r >> 16);
}

// W [256][256] fp32 -> WT [n][k] bf16
__global__ __launch_bounds__(256) void k_wt(const float* __restrict__ W, short* __restrict__ WT) {
    int k = blockIdx.x, n = threadIdx.x;
    WT[n * 256 + k] = f2bf(W[k * 256 + n]);
}

// Wh = h @ W  (M=8192, N=256, K=256), bf16 MFMA, 64x64 tile, BK=32
__global__ __launch_bounds__(256) void k_gemm1(const float* __restrict__ h, const short* __restrict__ WT,
                                               float* __restrict__ Wh) {
    __shared__ short sA[64 * 40];
    __shared__ short sB[64 * 40];
    int bm = blockIdx.x;   // 0..127
    int bn = blockIdx.y;   // 0..3
    int t  = threadIdx.x;
    int w = t >> 6, lane = t & 63, quad = lane >> 4, l16 = lane & 15;

    float4v acc[4];
#pragma unroll
    for (int c = 0; c < 4; c++)
#pragma unroll
        for (int j = 0; j < 4; j++) acc[c][j] = 0.f;

    int r  = t >> 2;            // 0..63
    int ko = (t & 3) * 8;       // 0,8,16,24

    for (int k0 = 0; k0 < 256; k0 += 32) {
        const float4v* src = (const float4v*)&h[(size_t)(64 * bm + r) * 256 + k0 + ko];
        float4v v0 = src[0], v1 = src[1];
        short8v pk;
        pk[0] = f2bf(v0[0]); pk[1] = f2bf(v0[1]); pk[2] = f2bf(v0[2]); pk[3] = f2bf(v0[3]);
        pk[4] = f2bf(v1[0]); pk[5] = f2bf(v1[1]); pk[6] = f2bf(v1[2]); pk[7] = f2bf(v1[3]);
        *(short8v*)&sA[r * 40 + ko] = pk;
        short8v bv = *(const short8v*)&WT[(size_t)(64 * bn + r) * 256 + k0 + ko];
        *(short8v*)&sB[r * 40 + ko] = bv;
        __syncthreads();

        short8v af = *(const short8v*)&sA[(16 * w + l16) * 40 + quad * 8];
#pragma unroll
        for (int c = 0; c < 4; c++) {
            short8v bf = *(const short8v*)&sB[(16 * c + l16) * 40 + quad * 8];
            acc[c] = __builtin_amdgcn_mfma_f32_16x16x32_bf16(af, bf, acc[c], 0, 0, 0);
        }
        __syncthreads();
    }
#pragma unroll
    for (int c = 0; c < 4; c++)
#pragma unroll
        for (int j = 0; j < 4; j++) {
            int row = 64 * bm + 16 * w + quad * 4 + j;
            int col = 64 * bn + 16 * c + l16;
            Wh[(size_t)row * 256 + col] = acc[c][j];
        }
}

// Wh1 = Wh@a1, Wh2 = Wh@a2, global max(Wh2) via encoded atomicMax. 4 rows/block (1/wave).
__global__ __launch_bounds__(256) void k_rowstats(const float* __restrict__ Wh, const float* __restrict__ a,
                                                  float* __restrict__ Wh1, float* __restrict__ Wh2,
                                                  unsigned* __restrict__ maxenc) {
    int w = threadIdx.x >> 6, lane = threadIdx.x & 63;
    int row = blockIdx.x * 4 + w;
    float s1 = 0.f, s2 = 0.f;
#pragma unroll
    for (int j = 0; j < 4; j++) {
        int c = lane + 64 * j;
        float v = Wh[(size_t)row * 256 + c];
        s1 += v * a[c];
        s2 += v * a[256 + c];
    }
#pragma unroll
    for (int off = 32; off; off >>= 1) {
        s1 += __shfl_down(s1, off);
        s2 += __shfl_down(s2, off);
    }
    if (lane == 0) {
        Wh1[row] = s1;
        Wh2[row] = s2;
        unsigned u = __float_as_uint(s2);
        unsigned key = (u & 0x80000000u) ? ~u : (u | 0x80000000u);
        atomicMax(maxenc, key);
    }
}

// WhT[n][k] bf16 from Wh[k][n] fp32, 64x64 LDS tile
__global__ __launch_bounds__(256) void k_transpose(const float* __restrict__ Wh, short* __restrict__ WhT) {
    __shared__ short sT[64 * 72];
    int bm = blockIdx.x, bn = blockIdx.y;
    int t = threadIdx.x;
#pragma unroll
    for (int i = 0; i < 4; i++) {
        int idx = i * 256 + t;
        int r = idx >> 4, c4 = (idx & 15) * 4;
        float4v v = *(const float4v*)&Wh[(size_t)(64 * bm + r) * 256 + 64 * bn + c4];
#pragma unroll
        for (int j = 0; j < 4; j++) sT[(c4 + j) * 72 + r] = f2bf(v[j]);
    }
    __syncthreads();
    int c = t >> 2, ro = (t & 3) * 16;
#pragma unroll
    for (int hh = 0; hh < 2; hh++) {
        short8v v = *(const short8v*)&sT[c * 72 + ro + 8 * hh];
        *(short8v*)&WhT[(size_t)(64 * bn + c) * 8192 + 64 * bm + ro + 8 * hh] = v;
    }
}

// Fused masked-softmax GEMM, K-split. Grid (256, S). Block: M=32 rows, K slice Ksub, N=256.
// Accumulates partial C into Cacc (atomicAdd) and partial row sums into Lacc (atomicAdd).
// B tile staged via global_load_lds (async DMA) into XOR-swizzled unpadded LDS.
__global__ __launch_bounds__(512, 8) void k_gat(const float* __restrict__ adj, const short* __restrict__ WhT,
                                                const float* __restrict__ Wh1, const float* __restrict__ Wh2,
                                                const unsigned* __restrict__ maxenc,
                                                float* __restrict__ Cacc, float* __restrict__ Lacc,
                                                int Ksub) {
    __shared__ short sB[256 * 64];   // unpadded: row n = 64 shorts (128B), chunk-XOR swizzled
    __shared__ short sA[32 * 72];    // padded
    int bm = blockIdx.x;
    int sidx = blockIdx.y;
    int kb = sidx * Ksub;
    int t = threadIdx.x;
    int lane = t & 63, quad = lane >> 4, l16 = lane & 15;
    int w = t >> 6;
    int rg = w & 1;        // row-group 0/1 (16 rows each)
    int cg = w >> 1;       // col-group 0..3 (64 cols each)

    // decode global max(Wh2)
    unsigned key = maxenc[0];
    unsigned u = (key & 0x80000000u) ? (key & 0x7fffffffu) : ~key;
    float maxw2 = __uint_as_float(u);

    int r  = t >> 4;          // staging row 0..31
    int kc = (t & 15) * 4;    // staging k offset 0..60
    float wh1r = Wh1[32 * bm + r];
    float sup = wh1r + maxw2;
    float ci = fmaxf(sup, 0.2f * sup);   // leaky_relu monotone => e_ij <= ci for all j

    const float* adj_row = &adj[(size_t)(32 * bm + r) * 8192];

    // global_load_lds: slot s = i*512 + t; LDS 16B-chunk L = s; row n = L>>3;
    // src chunk = (s&7)^(n&7)  (constant across i since i*512 is a multiple of 512)
    int schunk = (t & 7) ^ ((t >> 3) & 7);
    int n0 = t >> 3;                      // row for i=0 (advances by 64 per i)
    const short* gb0 = &WhT[(size_t)n0 * 8192 + kb + schunk * 8];
    short* lb0 = &sB[(w * 64 + lane) * 8];   // wave-uniform base + lane*16B

    float4v acc[4];
#pragma unroll
    for (int c = 0; c < 4; c++)
#pragma unroll
        for (int j = 0; j < 4; j++) acc[c][j] = 0.f;
    float lsum = 0.f;

    for (int k0 = 0; k0 < Ksub; k0 += 64) {
        // ---- async stage B: 256x64 bf16 via direct-to-LDS DMA (in flight during P compute)
#pragma unroll
        for (int i = 0; i < 4; i++) {
            __builtin_amdgcn_global_load_lds(
                (const __attribute__((address_space(1))) void*)(gb0 + (size_t)i * 64 * 8192 + k0),
                (__attribute__((address_space(3))) void*)(lb0 + i * 512 * 8),
                16, 0, 0);
        }
        // ---- stage A: compute P tile [32 x 64] from adj + rank-1 scores
        float4v av = *(const float4v*)&adj_row[kb + k0 + kc];
        float4v w2 = *(const float4v*)&Wh2[kb + k0 + kc];
        short4v pk;
#pragma unroll
        for (int j = 0; j < 4; j++) {
            float s = wh1r + w2[j];
            float f = fmaxf(s, 0.2f * s);        // leaky_relu(0.2)
            float p = __expf(f - ci);
            p = (av[j] > 0.f) ? p : 0.f;
            lsum += p;
            pk[j] = f2bf(p);
        }
        *(short4v*)&sA[r * 72 + kc] = pk;
        __syncthreads();   // drains vmcnt (DMA) + lds writes

#pragma unroll
        for (int kk = 0; kk < 2; kk++) {
            short8v af = *(const short8v*)&sA[(16 * rg + l16) * 72 + kk * 32 + quad * 8];
#pragma unroll
            for (int c = 0; c < 4; c++) {
                int n = 64 * cg + 16 * c + l16;
                int ch = (kk * 4 + quad) ^ (n & 7);
                short8v bf = *(const short8v*)&sB[n * 64 + ch * 8];
                acc[c] = __builtin_amdgcn_mfma_f32_16x16x32_bf16(af, bf, acc[c], 0, 0, 0);
            }
        }
        __syncthreads();
    }

    // reduce lsum across the 16 staging threads that share a row, then accumulate
#pragma unroll
    for (int off = 8; off; off >>= 1) lsum += __shfl_xor(lsum, off, 16);
    if ((lane & 15) == 0) atomicAdd(&Lacc[32 * bm + r], lsum);

#pragma unroll
    for (int c = 0; c < 4; c++)
#pragma unroll
        for (int j = 0; j < 4; j++) {
            int rl = 16 * rg + quad * 4 + j;
            int row = 32 * bm + rl;
            int col = 64 * cg + 16 * c + l16;
            atomicAdd(&Cacc[(size_t)row * 256 + col], acc[c][j]);
        }
}

// out = elu( Cacc / Lacc )
__global__ __launch_bounds__(256) void k_final(const float* __restrict__ Cacc, const float* __restrict__ Lacc,
                                               float* __restrict__ out) {
    int idx = blockIdx.x * 256 + threadIdx.x;     // one float4 per thread; 2048 blocks
    int row = idx >> 6;
    int c4 = (idx & 63) * 4;
    float4v v = *(const float4v*)&Cacc[(size_t)row * 256 + c4];
    float inv = 1.0f / fmaxf(Lacc[row], 1e-30f);
    float4v o;
#pragma unroll
    for (int j = 0; j < 4; j++) {
        float x = v[j] * inv;
        o[j] = (x > 0.f) ? x : (__expf(x) - 1.f);
    }
    *(float4v*)&out[(size_t)row * 256 + c4] = o;
}

extern "C" void kernel_launch(void* const* d_in, const int* in_sizes, int n_in,
                              void* d_out, int out_size, void* d_ws, size_t ws_size,
                              hipStream_t stream) {
    const float* h   = (const float*)d_in[0];
    const float* adj = (const float*)d_in[1];
    const float* W   = (const float*)d_in[2];
    const float* a   = (const float*)d_in[3];
    float* out = (float*)d_out;

    const int S = 4;
    const int Ksub = NN / S;

    // ws layout (12.8 MB total, same footprint as the round-1 run that passed):
    //  [0, 8MB)      Wh (fp32)  — dead after k_rowstats/k_transpose, then ALIASED as Cacc
    //  [8MB, 12MB)   WhT (bf16)
    //  tail: WT 128KB | Wh1 32KB | Wh2 32KB | Lacc 32KB | maxenc 4B
    char* ws = (char*)d_ws;
    float*    Wh     = (float*)(ws);
    float*    Cacc   = (float*)(ws);                 // alias of Wh (stream-ordered safe)
    short*    WhT    = (short*)(ws + 8388608);
    char*     tail   = ws + 12582912;
    short*    WT     = (short*)(tail);
    float*    Wh1    = (float*)(tail + 131072);
    float*    Wh2    = (float*)(tail + 163840);
    float*    Lacc   = (float*)(tail + 196608);
    unsigned* maxenc = (unsigned*)(tail + 229376);

    hipMemsetAsync(maxenc, 0, sizeof(unsigned), stream);

    k_wt<<<256, 256, 0, stream>>>(W, WT);
    k_gemm1<<<dim3(128, 4), 256, 0, stream>>>(h, WT, Wh);
    k_rowstats<<<2048, 256, 0, stream>>>(Wh, a, Wh1, Wh2, maxenc);
    k_transpose<<<dim3(128, 4), 256, 0, stream>>>(Wh, WhT);
    // Wh is dead now; zero it for use as Cacc, zero Lacc
    hipMemsetAsync(Cacc, 0, (size_t)NN * 256 * sizeof(float), stream);
    hipMemsetAsync(Lacc, 0, (size_t)NN * sizeof(float), stream);
    k_gat<<<dim3(256, S), 512, 0, stream>>>(adj, WhT, Wh1, Wh2, maxenc, Cacc, Lacc, Ksub);
    k_final<<<2048, 256, 0, stream>>>(Cacc, Lacc, out);
}

// Round 5
// 534.771 us; speedup vs baseline: 1.1618x; 1.0224x over previous
//
#include <hip/hip_runtime.h>
#include <hip/hip_bf16.h>
#include <stdint.h>

typedef __attribute__((ext_vector_type(4))) short short4v;
typedef __attribute__((ext_vector_type(8))) short short8v;
typedef __attribute__((ext_vector_type(4))) float float4v;

#define NN 8192
#define FIN 256
#define FOUT 256

__device__ __forceinline__ short f2bf(float f) {
    unsigned u = __float_as_uint(f);
    unsigned r = u + 0x7fffu + ((u >> 16) & 1u);   // RNE
    return (short)(r >> 16);
}

// W [256][256] fp32 -> WT [n][k] bf16
__global__ __launch_bounds__(256) void k_wt(const float* __restrict__ W, short* __restrict__ WT) {
    int k = blockIdx.x, n = threadIdx.x;
    WT[n * 256 + k] = f2bf(W[k * 256 + n]);
}

// Wh = h @ W  (M=8192, N=256, K=256), bf16 MFMA, 64x64 tile, BK=32
__global__ __launch_bounds__(256) void k_gemm1(const float* __restrict__ h, const short* __restrict__ WT,
                                               float* __restrict__ Wh) {
    __shared__ short sA[64 * 40];
    __shared__ short sB[64 * 40];
    int bm = blockIdx.x;   // 0..127
    int bn = blockIdx.y;   // 0..3
    int t  = threadIdx.x;
    int w = t >> 6, lane = t & 63, quad = lane >> 4, l16 = lane & 15;

    float4v acc[4];
#pragma unroll
    for (int c = 0; c < 4; c++)
#pragma unroll
        for (int j = 0; j < 4; j++) acc[c][j] = 0.f;

    int r  = t >> 2;            // 0..63
    int ko = (t & 3) * 8;       // 0,8,16,24

    for (int k0 = 0; k0 < 256; k0 += 32) {
        const float4v* src = (const float4v*)&h[(size_t)(64 * bm + r) * 256 + k0 + ko];
        float4v v0 = src[0], v1 = src[1];
        short8v pk;
        pk[0] = f2bf(v0[0]); pk[1] = f2bf(v0[1]); pk[2] = f2bf(v0[2]); pk[3] = f2bf(v0[3]);
        pk[4] = f2bf(v1[0]); pk[5] = f2bf(v1[1]); pk[6] = f2bf(v1[2]); pk[7] = f2bf(v1[3]);
        *(short8v*)&sA[r * 40 + ko] = pk;
        short8v bv = *(const short8v*)&WT[(size_t)(64 * bn + r) * 256 + k0 + ko];
        *(short8v*)&sB[r * 40 + ko] = bv;
        __syncthreads();

        short8v af = *(const short8v*)&sA[(16 * w + l16) * 40 + quad * 8];
#pragma unroll
        for (int c = 0; c < 4; c++) {
            short8v bf = *(const short8v*)&sB[(16 * c + l16) * 40 + quad * 8];
            acc[c] = __builtin_amdgcn_mfma_f32_16x16x32_bf16(af, bf, acc[c], 0, 0, 0);
        }
        __syncthreads();
    }
#pragma unroll
    for (int c = 0; c < 4; c++)
#pragma unroll
        for (int j = 0; j < 4; j++) {
            int row = 64 * bm + 16 * w + quad * 4 + j;
            int col = 64 * bn + 16 * c + l16;
            Wh[(size_t)row * 256 + col] = acc[c][j];
        }
}

// Wh1 = Wh@a1, Wh2 = Wh@a2, global max(Wh2) via encoded atomicMax. 4 rows/block (1/wave).
__global__ __launch_bounds__(256) void k_rowstats(const float* __restrict__ Wh, const float* __restrict__ a,
                                                  float* __restrict__ Wh1, float* __restrict__ Wh2,
                                                  unsigned* __restrict__ maxenc) {
    int w = threadIdx.x >> 6, lane = threadIdx.x & 63;
    int row = blockIdx.x * 4 + w;
    float s1 = 0.f, s2 = 0.f;
#pragma unroll
    for (int j = 0; j < 4; j++) {
        int c = lane + 64 * j;
        float v = Wh[(size_t)row * 256 + c];
        s1 += v * a[c];
        s2 += v * a[256 + c];
    }
#pragma unroll
    for (int off = 32; off; off >>= 1) {
        s1 += __shfl_down(s1, off);
        s2 += __shfl_down(s2, off);
    }
    if (lane == 0) {
        Wh1[row] = s1;
        Wh2[row] = s2;
        unsigned u = __float_as_uint(s2);
        unsigned key = (u & 0x80000000u) ? ~u : (u | 0x80000000u);
        atomicMax(maxenc, key);
    }
}

// WhT[n][k] bf16 from Wh[k][n] fp32, 64x64 LDS tile
__global__ __launch_bounds__(256) void k_transpose(const float* __restrict__ Wh, short* __restrict__ WhT) {
    __shared__ short sT[64 * 72];
    int bm = blockIdx.x, bn = blockIdx.y;
    int t = threadIdx.x;
#pragma unroll
    for (int i = 0; i < 4; i++) {
        int idx = i * 256 + t;
        int r = idx >> 4, c4 = (idx & 15) * 4;
        float4v v = *(const float4v*)&Wh[(size_t)(64 * bm + r) * 256 + 64 * bn + c4];
#pragma unroll
        for (int j = 0; j < 4; j++) sT[(c4 + j) * 72 + r] = f2bf(v[j]);
    }
    __syncthreads();
    int c = t >> 2, ro = (t & 3) * 16;
#pragma unroll
    for (int hh = 0; hh < 2; hh++) {
        short8v v = *(const short8v*)&sT[c * 72 + ro + 8 * hh];
        *(short8v*)&WhT[(size_t)(64 * bn + c) * 8192 + 64 * bm + ro + 8 * hh] = v;
    }
}

// Fused masked-softmax GEMM, K-split. Grid (128, S). Block: M=64 rows, K slice Ksub, N=256.
// 1024 threads / 16 waves. B tile via global_load_lds into XOR-swizzled LDS.
// adj/Wh2 register-prefetched one K-iter ahead so their HBM latency drains with the DMA.
// launch_bounds (1024,4): VGPR cap 128 (kernel should land <=64 naturally -> 2 blocks/CU).
__global__ __launch_bounds__(1024, 4) void k_gat(const float* __restrict__ adj, const short* __restrict__ WhT,
                                                 const float* __restrict__ Wh1, const float* __restrict__ Wh2,
                                                 const unsigned* __restrict__ maxenc,
                                                 float* __restrict__ Cacc, float* __restrict__ Lacc,
                                                 int Ksub) {
    __shared__ short sB[256 * 64];   // unpadded: row n = 64 shorts (128B), chunk-XOR swizzled
    __shared__ short sA[64 * 72];    // padded
    int bm = blockIdx.x;             // 0..127 (64 rows each)
    int sidx = blockIdx.y;
    int kb = sidx * Ksub;
    int t = threadIdx.x;
    int lane = t & 63, quad = lane >> 4, l16 = lane & 15;
    int w = t >> 6;                  // 0..15
    int rg = w & 3;                  // row-group 0..3 (16 rows each)
    int cg = w >> 2;                 // col-group 0..3 (64 cols each)

    // decode global max(Wh2)
    unsigned key = maxenc[0];
    unsigned u = (key & 0x80000000u) ? (key & 0x7fffffffu) : ~key;
    float maxw2 = __uint_as_float(u);

    int r  = t >> 4;          // staging row 0..63
    int kc = (t & 15) * 4;    // staging k offset 0..60
    float wh1r = Wh1[64 * bm + r];
    float sup = wh1r + maxw2;
    float ci = fmaxf(sup, 0.2f * sup);   // leaky_relu monotone => e_ij <= ci for all j

    const float* adj_row = &adj[(size_t)(64 * bm + r) * 8192 + kb];
    const float* w2base  = &Wh2[kb];

    // global_load_lds: chunk s = i*1024 + t (i=0,1); row n = s>>3 = i*128 + (t>>3);
    // src chunk = (s&7)^(n&7) — constant across i.
    int schunk = (t & 7) ^ ((t >> 3) & 7);
    const short* gb0 = &WhT[(size_t)(t >> 3) * 8192 + kb + schunk * 8];
    short* lb0 = &sB[(w * 64 + lane) * 8];   // wave-uniform base + lane*16B

    float4v acc[4];
#pragma unroll
    for (int c = 0; c < 4; c++)
#pragma unroll
        for (int j = 0; j < 4; j++) acc[c][j] = 0.f;
    float lsum = 0.f;

    // prefetch iter 0's adj + w2
    float4v av = *(const float4v*)&adj_row[kc];
    float4v w2 = *(const float4v*)&w2base[kc];

    for (int k0 = 0; k0 < Ksub; k0 += 64) {
        // ---- async stage B: 256x64 bf16 via direct-to-LDS DMA
#pragma unroll
        for (int i = 0; i < 2; i++) {
            __builtin_amdgcn_global_load_lds(
                (const __attribute__((address_space(1))) void*)(gb0 + (size_t)i * 128 * 8192 + k0),
                (__attribute__((address_space(3))) void*)(lb0 + i * 1024 * 8),
                16, 0, 0);
        }
        // ---- stage A: compute P tile [64 x 64] from prefetched adj + rank-1 scores
        short4v pk;
#pragma unroll
        for (int j = 0; j < 4; j++) {
            float s = wh1r + w2[j];
            float f = fmaxf(s, 0.2f * s);        // leaky_relu(0.2)
            float p = __expf(f - ci);
            p = (av[j] > 0.f) ? p : 0.f;
            lsum += p;
            pk[j] = f2bf(p);
        }
        *(short4v*)&sA[r * 72 + kc] = pk;
        // ---- prefetch next iter's adj + w2 (latency overlaps the barrier drain + MFMA)
        if (k0 + 64 < Ksub) {
            av = *(const float4v*)&adj_row[k0 + 64 + kc];
            w2 = *(const float4v*)&w2base[k0 + 64 + kc];
        }
        __syncthreads();   // drains DMA + prefetch vmcnt + LDS writes

#pragma unroll
        for (int kk = 0; kk < 2; kk++) {
            short8v af = *(const short8v*)&sA[(16 * rg + l16) * 72 + kk * 32 + quad * 8];
#pragma unroll
            for (int c = 0; c < 4; c++) {
                int n = 64 * cg + 16 * c + l16;
                int ch = (kk * 4 + quad) ^ (n & 7);
                short8v bf = *(const short8v*)&sB[n * 64 + ch * 8];
                acc[c] = __builtin_amdgcn_mfma_f32_16x16x32_bf16(af, bf, acc[c], 0, 0, 0);
            }
        }
        __syncthreads();
    }

    // reduce lsum across the 16 staging threads that share a row, then accumulate
#pragma unroll
    for (int off = 8; off; off >>= 1) lsum += __shfl_xor(lsum, off, 16);
    if ((lane & 15) == 0) atomicAdd(&Lacc[64 * bm + r], lsum);

#pragma unroll
    for (int c = 0; c < 4; c++)
#pragma unroll
        for (int j = 0; j < 4; j++) {
            int rl = 16 * rg + quad * 4 + j;
            int row = 64 * bm + rl;
            int col = 64 * cg + 16 * c + l16;
            atomicAdd(&Cacc[(size_t)row * 256 + col], acc[c][j]);
        }
}

// out = elu( Cacc / Lacc )
__global__ __launch_bounds__(256) void k_final(const float* __restrict__ Cacc, const float* __restrict__ Lacc,
                                               float* __restrict__ out) {
    int idx = blockIdx.x * 256 + threadIdx.x;     // one float4 per thread; 2048 blocks
    int row = idx >> 6;
    int c4 = (idx & 63) * 4;
    float4v v = *(const float4v*)&Cacc[(size_t)row * 256 + c4];
    float inv = 1.0f / fmaxf(Lacc[row], 1e-30f);
    float4v o;
#pragma unroll
    for (int j = 0; j < 4; j++) {
        float x = v[j] * inv;
        o[j] = (x > 0.f) ? x : (__expf(x) - 1.f);
    }
    *(float4v*)&out[(size_t)row * 256 + c4] = o;
}

extern "C" void kernel_launch(void* const* d_in, const int* in_sizes, int n_in,
                              void* d_out, int out_size, void* d_ws, size_t ws_size,
                              hipStream_t stream) {
    const float* h   = (const float*)d_in[0];
    const float* adj = (const float*)d_in[1];
    const float* W   = (const float*)d_in[2];
    const float* a   = (const float*)d_in[3];
    float* out = (float*)d_out;

    const int S = 4;
    const int Ksub = NN / S;

    // ws layout (12.8 MB):
    //  [0, 8MB)      Wh (fp32)  — dead after k_rowstats/k_transpose, then ALIASED as Cacc
    //  [8MB, 12MB)   WhT (bf16)
    //  tail: WT 128KB | Wh1 32KB | Wh2 32KB | Lacc 32KB | maxenc 4B
    char* ws = (char*)d_ws;
    float*    Wh     = (float*)(ws);
    float*    Cacc   = (float*)(ws);                 // alias of Wh (stream-ordered safe)
    short*    WhT    = (short*)(ws + 8388608);
    char*     tail   = ws + 12582912;
    short*    WT     = (short*)(tail);
    float*    Wh1    = (float*)(tail + 131072);
    float*    Wh2    = (float*)(tail + 163840);
    float*    Lacc   = (float*)(tail + 196608);
    unsigned* maxenc = (unsigned*)(tail + 229376);

    hipMemsetAsync(maxenc, 0, sizeof(unsigned), stream);

    k_wt<<<256, 256, 0, stream>>>(W, WT);
    k_gemm1<<<dim3(128, 4), 256, 0, stream>>>(h, WT, Wh);
    k_rowstats<<<2048, 256, 0, stream>>>(Wh, a, Wh1, Wh2, maxenc);
    k_transpose<<<dim3(128, 4), 256, 0, stream>>>(Wh, WhT);
    // Wh is dead now; zero it for use as Cacc, zero Lacc
    hipMemsetAsync(Cacc, 0, (size_t)NN * 256 * sizeof(float), stream);
    hipMemsetAsync(Lacc, 0, (size_t)NN * sizeof(float), stream);
    k_gat<<<dim3(128, S), 1024, 0, stream>>>(adj, WhT, Wh1, Wh2, maxenc, Cacc, Lacc, Ksub);
    k_final<<<2048, 256, 0, stream>>>(Cacc, Lacc, out);
}